// Round 1
// baseline (480.238 us; speedup 1.0000x reference)
//
#include <hip/hip_runtime.h>

#define SEQ 2048
#define EMBED 1024
#define DHEAD 64

typedef _Float16 h8 __attribute__((ext_vector_type(8)));
typedef float f4 __attribute__((ext_vector_type(4)));

#define LSTR 56   // GEMM LDS row stride in halves (112 B: 16B-aligned, 2-way bank alias)
#define ASTR 72   // attention LDS row stride in halves (144 B: 16B-aligned, 2-way alias)

// ---------------- shared 128x128 BT-GEMM core: C = A[M,1024] * W[N,1024]^T ----------------
__device__ __forceinline__ void gemm128_bt(const float* __restrict__ A,
                                           const float* __restrict__ W,
                                           int m0, int n0, int tid, f4 acc[4][4])
{
    __shared__ _Float16 As[128 * LSTR];
    __shared__ _Float16 Bs[128 * LSTR];
    const int lane = tid & 63;
    const int wave = tid >> 6;
    const int wm = (wave >> 1) * 64;
    const int wn = (wave & 1) * 64;
    const int t16 = lane & 15;
    const int quad = lane >> 4;
    const int sr = tid >> 3;   // 0..31 staging row base
    const int sc = tid & 7;    // 0..7 float4 column

    for (int k0 = 0; k0 < 1024; k0 += 32) {
        __syncthreads();
#pragma unroll
        for (int rr = 0; rr < 4; ++rr) {
            int row = rr * 32 + sr;
            float4 va = *((const float4*)(A + (size_t)(m0 + row) * 1024 + k0) + sc);
            float4 vb = *((const float4*)(W + (size_t)(n0 + row) * 1024 + k0) + sc);
            _Float16* pa = As + row * LSTR + sc * 4;
            pa[0] = (_Float16)va.x; pa[1] = (_Float16)va.y;
            pa[2] = (_Float16)va.z; pa[3] = (_Float16)va.w;
            _Float16* pb = Bs + row * LSTR + sc * 4;
            pb[0] = (_Float16)vb.x; pb[1] = (_Float16)vb.y;
            pb[2] = (_Float16)vb.z; pb[3] = (_Float16)vb.w;
        }
        __syncthreads();
        h8 af[4], bf[4];
#pragma unroll
        for (int i = 0; i < 4; ++i)
            af[i] = *(const h8*)(As + (wm + i * 16 + t16) * LSTR + quad * 8);
#pragma unroll
        for (int j = 0; j < 4; ++j)
            bf[j] = *(const h8*)(Bs + (wn + j * 16 + t16) * LSTR + quad * 8);
#pragma unroll
        for (int i = 0; i < 4; ++i)
#pragma unroll
            for (int j = 0; j < 4; ++j)
                acc[i][j] = __builtin_amdgcn_mfma_f32_16x16x32_f16(af[i], bf[j], acc[i][j], 0, 0, 0);
    }
}

// ---------------- fused QKV projection; z=0:Q z=1:K (headsplit [B,H,S,d]) z=2:V (transposed [B,H,d,S]) ----------------
__global__ __launch_bounds__(256) void proj_qkv(
    const float* __restrict__ query, const float* __restrict__ key, const float* __restrict__ value,
    const float* __restrict__ Wq, const float* __restrict__ Wk, const float* __restrict__ Wv,
    _Float16* __restrict__ Qh, _Float16* __restrict__ Kh, _Float16* __restrict__ Vt)
{
    const int tid = threadIdx.x;
    const int m0 = blockIdx.x * 128, n0 = blockIdx.y * 128;
    const int z = blockIdx.z;
    const float* A = (z == 0) ? query : (z == 1) ? key : value;
    const float* W = (z == 0) ? Wq : (z == 1) ? Wk : Wv;
    _Float16* dst = (z == 0) ? Qh : (z == 1) ? Kh : Vt;

    f4 acc[4][4];
    const f4 z4 = {0.f, 0.f, 0.f, 0.f};
#pragma unroll
    for (int i = 0; i < 4; ++i)
#pragma unroll
        for (int j = 0; j < 4; ++j) acc[i][j] = z4;

    gemm128_bt(A, W, m0, n0, tid, acc);

    const int lane = tid & 63, wave = tid >> 6;
    const int t16 = lane & 15, quad = lane >> 4;
    const int wm = (wave >> 1) * 64, wn = (wave & 1) * 64;
#pragma unroll
    for (int i = 0; i < 4; ++i)
#pragma unroll
        for (int j = 0; j < 4; ++j)
#pragma unroll
            for (int reg = 0; reg < 4; ++reg) {
                int gm = m0 + wm + i * 16 + quad * 4 + reg;   // row = b*S+s
                int gn = n0 + wn + j * 16 + t16;              // col = h*64+dd
                int b = gm >> 11, s = gm & 2047, h = gn >> 6, dd = gn & 63;
                float v = acc[i][j][reg];
                if (z < 2)
                    dst[(((size_t)(b * 16 + h) * SEQ) + s) * DHEAD + dd] = (_Float16)v;
                else
                    dst[(((size_t)(b * 16 + h) * DHEAD) + dd) * SEQ + s] = (_Float16)v;
            }
}

// ---------------- causal flash attention: one block = (b,h) x 64 q-rows ----------------
__global__ __launch_bounds__(256) void attn_kernel(
    const _Float16* __restrict__ Qh, const _Float16* __restrict__ Kh,
    const _Float16* __restrict__ Vt, float* __restrict__ O)
{
    const int tid = threadIdx.x;
    const int lane = tid & 63, wave = tid >> 6;
    const int t16 = lane & 15, quad = lane >> 4;
    const int bh = blockIdx.x;
    const int b = bh >> 4, h = bh & 15;
    const int q0 = blockIdx.y * 64;

    const _Float16* Qp = Qh + (size_t)bh * SEQ * DHEAD;
    const _Float16* Kp = Kh + (size_t)bh * SEQ * DHEAD;
    const _Float16* Vp = Vt + (size_t)bh * DHEAD * SEQ;

    __shared__ _Float16 Ks[64 * ASTR];
    __shared__ _Float16 Vs[64 * ASTR];
    __shared__ _Float16 Qs[64 * ASTR];   // reused as P after q-frags are in registers

    // stage Q tile [64 x 64]
#pragma unroll
    for (int p = 0; p < 2; ++p) {
        int idx = tid + p * 256;
        int row = idx >> 3, c = idx & 7;
        *(h8*)(Qs + row * ASTR + c * 8) = *(const h8*)(Qp + (size_t)(q0 + row) * DHEAD + c * 8);
    }
    __syncthreads();
    h8 qf[2];
    qf[0] = *(const h8*)(Qs + (wave * 16 + t16) * ASTR + quad * 8);
    qf[1] = *(const h8*)(Qs + (wave * 16 + t16) * ASTR + 32 + quad * 8);
    __syncthreads();

    float m_r[4] = {-1e30f, -1e30f, -1e30f, -1e30f};
    float l_r[4] = {0.f, 0.f, 0.f, 0.f};
    f4 o_acc[4];
    const f4 z4 = {0.f, 0.f, 0.f, 0.f};
#pragma unroll
    for (int dt = 0; dt < 4; ++dt) o_acc[dt] = z4;

    const int nt = q0 / 64 + 1;
    for (int jt = 0; jt < nt; ++jt) {
        // stage K tile [64j x 64d] and V^T tile [64d x 64j]
#pragma unroll
        for (int p = 0; p < 2; ++p) {
            int idx = tid + p * 256;
            int row = idx >> 3, c = idx & 7;
            *(h8*)(Ks + row * ASTR + c * 8) = *(const h8*)(Kp + (size_t)(jt * 64 + row) * DHEAD + c * 8);
            *(h8*)(Vs + row * ASTR + c * 8) = *(const h8*)(Vp + (size_t)row * SEQ + jt * 64 + c * 8);
        }
        __syncthreads();

        // S = Q K^T
        f4 s_acc[4];
#pragma unroll
        for (int j4 = 0; j4 < 4; ++j4) s_acc[j4] = z4;
#pragma unroll
        for (int j4 = 0; j4 < 4; ++j4) {
            h8 kf0 = *(const h8*)(Ks + (j4 * 16 + t16) * ASTR + quad * 8);
            h8 kf1 = *(const h8*)(Ks + (j4 * 16 + t16) * ASTR + 32 + quad * 8);
            s_acc[j4] = __builtin_amdgcn_mfma_f32_16x16x32_f16(qf[0], kf0, s_acc[j4], 0, 0, 0);
            s_acc[j4] = __builtin_amdgcn_mfma_f32_16x16x32_f16(qf[1], kf1, s_acc[j4], 0, 0, 0);
        }

        // scale + causal mask + per-row max (C-layout: row = quad*4+reg, col = t16)
        const bool diag = (jt == nt - 1);
        float mrow[4];
#pragma unroll
        for (int reg = 0; reg < 4; ++reg) {
            int ig = q0 + wave * 16 + quad * 4 + reg;
            float mx = -1e30f;
#pragma unroll
            for (int j4 = 0; j4 < 4; ++j4) {
                float s = s_acc[j4][reg] * 0.125f;
                if (diag) {
                    int jg = jt * 64 + j4 * 16 + t16;
                    if (jg > ig) s = -1e30f;
                }
                s_acc[j4][reg] = s;
                mx = fmaxf(mx, s);
            }
            mrow[reg] = mx;
        }
#pragma unroll
        for (int off = 1; off < 16; off <<= 1)
#pragma unroll
            for (int reg = 0; reg < 4; ++reg)
                mrow[reg] = fmaxf(mrow[reg], __shfl_xor(mrow[reg], off, 64));

        float alpha[4], rsum[4];
#pragma unroll
        for (int reg = 0; reg < 4; ++reg) {
            float mnew = fmaxf(m_r[reg], mrow[reg]);
            alpha[reg] = __expf(m_r[reg] - mnew);
            m_r[reg] = mnew;
            float rs = 0.f;
#pragma unroll
            for (int j4 = 0; j4 < 4; ++j4) {
                float p = __expf(s_acc[j4][reg] - mnew);
                s_acc[j4][reg] = p;
                rs += p;
            }
            rsum[reg] = rs;
        }
#pragma unroll
        for (int off = 1; off < 16; off <<= 1)
#pragma unroll
            for (int reg = 0; reg < 4; ++reg)
                rsum[reg] += __shfl_xor(rsum[reg], off, 64);
#pragma unroll
        for (int reg = 0; reg < 4; ++reg)
            l_r[reg] = l_r[reg] * alpha[reg] + rsum[reg];

        // P: C-layout -> LDS -> A-layout (each wave owns rows wave*16..+15 of Qs/Ps)
#pragma unroll
        for (int j4 = 0; j4 < 4; ++j4)
#pragma unroll
            for (int reg = 0; reg < 4; ++reg)
                Qs[(wave * 16 + quad * 4 + reg) * ASTR + j4 * 16 + t16] = (_Float16)s_acc[j4][reg];
        __syncthreads();

        // rescale O accumulator, then O += P V
#pragma unroll
        for (int dt = 0; dt < 4; ++dt)
#pragma unroll
            for (int reg = 0; reg < 4; ++reg)
                o_acc[dt][reg] *= alpha[reg];
        h8 pf0 = *(const h8*)(Qs + (wave * 16 + t16) * ASTR + quad * 8);
        h8 pf1 = *(const h8*)(Qs + (wave * 16 + t16) * ASTR + 32 + quad * 8);
#pragma unroll
        for (int dt = 0; dt < 4; ++dt) {
            h8 vf0 = *(const h8*)(Vs + (dt * 16 + t16) * ASTR + quad * 8);
            h8 vf1 = *(const h8*)(Vs + (dt * 16 + t16) * ASTR + 32 + quad * 8);
            o_acc[dt] = __builtin_amdgcn_mfma_f32_16x16x32_f16(pf0, vf0, o_acc[dt], 0, 0, 0);
            o_acc[dt] = __builtin_amdgcn_mfma_f32_16x16x32_f16(pf1, vf1, o_acc[dt], 0, 0, 0);
        }
        __syncthreads();
    }

    // write O merged-head [B,S,E] fp32
#pragma unroll
    for (int dt = 0; dt < 4; ++dt)
#pragma unroll
        for (int reg = 0; reg < 4; ++reg) {
            int s = q0 + wave * 16 + quad * 4 + reg;
            int dd = dt * 16 + t16;
            O[((size_t)(b * SEQ + s)) * EMBED + h * DHEAD + dd] = o_acc[dt][reg] / l_r[reg];
        }
}

// ---------------- output projection: out = O * Wo^T (fp32 out) ----------------
__global__ __launch_bounds__(256) void proj_out(
    const float* __restrict__ A, const float* __restrict__ Wo, float* __restrict__ out)
{
    const int tid = threadIdx.x;
    const int m0 = blockIdx.x * 128, n0 = blockIdx.y * 128;
    f4 acc[4][4];
    const f4 z4 = {0.f, 0.f, 0.f, 0.f};
#pragma unroll
    for (int i = 0; i < 4; ++i)
#pragma unroll
        for (int j = 0; j < 4; ++j) acc[i][j] = z4;

    gemm128_bt(A, Wo, m0, n0, tid, acc);

    const int lane = tid & 63, wave = tid >> 6;
    const int t16 = lane & 15, quad = lane >> 4;
    const int wm = (wave >> 1) * 64, wn = (wave & 1) * 64;
#pragma unroll
    for (int i = 0; i < 4; ++i)
#pragma unroll
        for (int j = 0; j < 4; ++j)
#pragma unroll
            for (int reg = 0; reg < 4; ++reg) {
                int gm = m0 + wm + i * 16 + quad * 4 + reg;
                int gn = n0 + wn + j * 16 + t16;
                out[(size_t)gm * EMBED + gn] = acc[i][j][reg];
            }
}

extern "C" void kernel_launch(void* const* d_in, const int* in_sizes, int n_in,
                              void* d_out, int out_size, void* d_ws, size_t ws_size,
                              hipStream_t stream) {
    const float* key   = (const float*)d_in[0];
    const float* query = (const float*)d_in[1];
    const float* value = (const float*)d_in[2];
    // d_in[3] = mask: causal tril, hardcoded in attn_kernel
    const float* Wq = (const float*)d_in[4];
    const float* Wk = (const float*)d_in[5];
    const float* Wv = (const float*)d_in[6];
    const float* Wo = (const float*)d_in[7];

    char* ws = (char*)d_ws;
    _Float16* Qh = (_Float16*)(ws);                    // 16 MB  [B,H,S,d] f16
    _Float16* Kh = (_Float16*)(ws + (16u << 20));      // 16 MB  [B,H,S,d] f16
    _Float16* Vt = (_Float16*)(ws + (32u << 20));      // 16 MB  [B,H,d,S] f16
    float*    Ob = (float*)   (ws + (48u << 20));      // 32 MB  [B,S,E] fp32

    dim3 blk(256);
    proj_qkv<<<dim3(64, 8, 3), blk, 0, stream>>>(query, key, value, Wq, Wk, Wv, Qh, Kh, Vt);
    attn_kernel<<<dim3(64, 32), blk, 0, stream>>>(Qh, Kh, Vt, Ob);
    proj_out<<<dim3(64, 8), blk, 0, stream>>>(Ob, Wo, (float*)d_out);
}

// Round 2
// 389.518 us; speedup vs baseline: 1.2329x; 1.2329x over previous
//
#include <hip/hip_runtime.h>

#define SEQ 2048
#define EMBED 1024
#define DHEAD 64

typedef _Float16 h8 __attribute__((ext_vector_type(8)));
typedef _Float16 h4 __attribute__((ext_vector_type(4)));
typedef float f4 __attribute__((ext_vector_type(4)));
typedef unsigned int u32;

// async global->LDS 16B copy. LDS dest must be wave-uniform base + lane*16.
__device__ __forceinline__ void gload_lds16(const void* g, void* l) {
    __builtin_amdgcn_global_load_lds(
        (const __attribute__((address_space(1))) u32*)g,
        (__attribute__((address_space(3))) u32*)l, 16, 0, 0);
}

// ---------------- fp32 -> f16 conversion pass (Wq pre-scaled by 0.125*log2(e)) ----------------
__global__ __launch_bounds__(256) void cvt_f16(
    const float* __restrict__ q, const float* __restrict__ k, const float* __restrict__ v,
    const float* __restrict__ wq, const float* __restrict__ wk, const float* __restrict__ wv,
    const float* __restrict__ wo,
    _Float16* __restrict__ q16, _Float16* __restrict__ k16, _Float16* __restrict__ v16,
    _Float16* __restrict__ wq16, _Float16* __restrict__ wk16, _Float16* __restrict__ wv16,
    _Float16* __restrict__ wo16)
{
    int bid = blockIdx.x;
    const float* src;
    _Float16* dst;
    float scale = 1.0f;
    size_t base;
    if (bid < 24576) {
        int seg = bid >> 13;
        base = (size_t)(bid & 8191) * 1024 + threadIdx.x * 4;
        src = seg == 0 ? q : seg == 1 ? k : v;
        dst = seg == 0 ? q16 : seg == 1 ? k16 : v16;
    } else {
        int wb = bid - 24576;
        int seg = wb >> 10;
        base = (size_t)(wb & 1023) * 1024 + threadIdx.x * 4;
        src = seg == 0 ? wq : seg == 1 ? wk : seg == 2 ? wv : wo;
        dst = seg == 0 ? wq16 : seg == 1 ? wk16 : seg == 2 ? wv16 : wo16;
        if (seg == 0) scale = 0.18033688011112042f;  // 0.125 * log2(e)
    }
    float4 x = *(const float4*)(src + base);
    h4 y = { (_Float16)(x.x * scale), (_Float16)(x.y * scale),
             (_Float16)(x.z * scale), (_Float16)(x.w * scale) };
    *(h4*)(dst + base) = y;
}

// ---------------- m97-style f16 GEMM core: C[128x128] = A * W^T, K=1024, BK=32 ----------------
// LDS tile layout: natural row-major [128][32] halves (64B rows; row stride 16 dwords -> 8/bank min).
__device__ __forceinline__ void gemm_core(const _Float16* __restrict__ A, const _Float16* __restrict__ W,
                                          int m0, int n0, int tid,
                                          _Float16* As, _Float16* Bs, f4 acc[4][4])
{
    const int lane = tid & 63, wave = tid >> 6;
    const int t16 = lane & 15, quad = lane >> 4;
    const int wm = (wave >> 1) * 64, wn = (wave & 1) * 64;
    const int wb = wave * 64;
    // unit u = r*4 + c  (r in [0,128), c in [0,4) 16B chunks); lanes stage u = p*256 + tid
    const int u0 = tid, u1 = tid + 256;
    const int r0 = u0 >> 2, c0 = u0 & 3;
    const int r1 = u1 >> 2, c1 = u1 & 3;
    const _Float16* ga0 = A + (size_t)(m0 + r0) * 1024 + c0 * 8;
    const _Float16* ga1 = A + (size_t)(m0 + r1) * 1024 + c1 * 8;
    const _Float16* gb0 = W + (size_t)(n0 + r0) * 1024 + c0 * 8;
    const _Float16* gb1 = W + (size_t)(n0 + r1) * 1024 + c1 * 8;
    _Float16* la0 = As + wb * 8;
    _Float16* la1 = As + (256 + wb) * 8;
    _Float16* lb0 = Bs + wb * 8;
    _Float16* lb1 = Bs + (256 + wb) * 8;

    for (int k0 = 0; k0 < 1024; k0 += 32) {
        __syncthreads();
        gload_lds16(ga0 + k0, la0);
        gload_lds16(ga1 + k0, la1);
        gload_lds16(gb0 + k0, lb0);
        gload_lds16(gb1 + k0, lb1);
        __syncthreads();
        h8 af[4], bf[4];
#pragma unroll
        for (int i = 0; i < 4; ++i)
            af[i] = *(const h8*)(As + (wm + i * 16 + t16) * 32 + quad * 8);
#pragma unroll
        for (int j = 0; j < 4; ++j)
            bf[j] = *(const h8*)(Bs + (wn + j * 16 + t16) * 32 + quad * 8);
#pragma unroll
        for (int i = 0; i < 4; ++i)
#pragma unroll
            for (int j = 0; j < 4; ++j)
                acc[i][j] = __builtin_amdgcn_mfma_f32_16x16x32_f16(af[i], bf[j], acc[i][j], 0, 0, 0);
    }
}

// ---------------- fused QKV projection ----------------
// z=0: Q = q16 @ Wq'^T -> Qh [B,H,S,d]   z=1: K -> Kh [B,H,S,d]
// z=2: V^T = Wv @ v16^T -> Vt [B,H,d,S]  (operands swapped so epilogue stays coalesced)
__global__ __launch_bounds__(256) void proj_qkv(
    const _Float16* __restrict__ q16, const _Float16* __restrict__ k16, const _Float16* __restrict__ v16,
    const _Float16* __restrict__ Wq, const _Float16* __restrict__ Wk, const _Float16* __restrict__ Wv,
    _Float16* __restrict__ Qh, _Float16* __restrict__ Kh, _Float16* __restrict__ Vt)
{
    __shared__ _Float16 As[4096], Bs[4096];
    const int tid = threadIdx.x;
    const int z = blockIdx.z;
    const _Float16 *A, *W;
    int m0, n0;
    if (z == 2) { A = Wv; W = v16; m0 = blockIdx.y * 128; n0 = blockIdx.x * 128; }
    else if (z == 0) { A = q16; W = Wq; m0 = blockIdx.x * 128; n0 = blockIdx.y * 128; }
    else { A = k16; W = Wk; m0 = blockIdx.x * 128; n0 = blockIdx.y * 128; }

    f4 acc[4][4];
    const f4 z4 = {0.f, 0.f, 0.f, 0.f};
#pragma unroll
    for (int i = 0; i < 4; ++i)
#pragma unroll
        for (int j = 0; j < 4; ++j) acc[i][j] = z4;

    gemm_core(A, W, m0, n0, tid, As, Bs, acc);

    const int lane = tid & 63, wave = tid >> 6;
    const int t16 = lane & 15, quad = lane >> 4;
    const int wm = (wave >> 1) * 64, wn = (wave & 1) * 64;
#pragma unroll
    for (int i = 0; i < 4; ++i)
#pragma unroll
        for (int j = 0; j < 4; ++j)
#pragma unroll
            for (int reg = 0; reg < 4; ++reg) {
                int gm = m0 + wm + i * 16 + quad * 4 + reg;
                int gn = n0 + wn + j * 16 + t16;
                float vv = acc[i][j][reg];
                if (z < 2) {
                    int b = gm >> 11, s = gm & 2047, h = gn >> 6, dd = gn & 63;
                    _Float16* dst = (z == 0) ? Qh : Kh;
                    dst[(((size_t)(b * 16 + h) * SEQ) + s) * DHEAD + dd] = (_Float16)vv;
                } else {
                    int h = gm >> 6, dd = gm & 63, b = gn >> 11, s = gn & 2047;
                    Vt[(((size_t)(b * 16 + h) * DHEAD) + dd) * SEQ + s] = (_Float16)vv;
                }
            }
}

// ---------------- causal flash attention ----------------
// block = (b,h) x 64 q-rows, 4 waves. K/V double-buffered via global_load_lds (1 barrier/tile).
// LDS K/V tiles: row-major [64][8 chunks], chunk slot XOR-swizzled by (row&7) to kill
// the 128B-row-stride bank degeneracy. P round-trip: f32, stride 68 (same-wave only, no barrier).
__global__ __launch_bounds__(256) void attn2(
    const _Float16* __restrict__ Qh, const _Float16* __restrict__ Kh,
    const _Float16* __restrict__ Vt, _Float16* __restrict__ Ob)
{
    __shared__ _Float16 KVs[2][2][4096];
    __shared__ float Ps[64 * 68];
    const int tid = threadIdx.x;
    const int lane = tid & 63, wave = tid >> 6;
    const int t16 = lane & 15, quad = lane >> 4;
    const int bh = blockIdx.x;
    const int b = bh >> 4, h = bh & 15;
    const int qb = (gridDim.y - 1) - blockIdx.y;   // heavy blocks launch first
    const int q0 = qb * 64;
    const int nt = qb + 1;

    const _Float16* Qp = Qh + (size_t)bh * SEQ * DHEAD;
    const _Float16* Kp = Kh + (size_t)bh * SEQ * DHEAD;
    const _Float16* Vp = Vt + (size_t)bh * DHEAD * SEQ;

    // Q fragments straight from global (coalesced, 16B aligned)
    h8 qf0 = *(const h8*)(Qp + (size_t)(q0 + wave * 16 + t16) * 64 + quad * 8);
    h8 qf1 = *(const h8*)(Qp + (size_t)(q0 + wave * 16 + t16) * 64 + 32 + quad * 8);

    const int wb = wave * 64;
    // staging: unit u = r*8 + c_lds; global chunk = c_lds ^ (r&7)
    const int sr0 = tid >> 3,          sc0 = (tid & 7) ^ (sr0 & 7);
    const int sr1 = (tid + 256) >> 3,  sc1 = ((tid + 256) & 7) ^ (sr1 & 7);

#define STAGE(jt, bufi)                                                                     \
    do {                                                                                    \
        gload_lds16(Kp + (size_t)((jt) * 64 + sr0) * 64 + sc0 * 8, &KVs[bufi][0][wb * 8]);  \
        gload_lds16(Kp + (size_t)((jt) * 64 + sr1) * 64 + sc1 * 8, &KVs[bufi][0][(256 + wb) * 8]); \
        gload_lds16(Vp + (size_t)sr0 * SEQ + (jt) * 64 + sc0 * 8, &KVs[bufi][1][wb * 8]);   \
        gload_lds16(Vp + (size_t)sr1 * SEQ + (jt) * 64 + sc1 * 8, &KVs[bufi][1][(256 + wb) * 8]); \
    } while (0)

    STAGE(0, 0);
    __syncthreads();

    float m_r[4] = {-1e30f, -1e30f, -1e30f, -1e30f};
    float l_r[4] = {0.f, 0.f, 0.f, 0.f};
    f4 o_acc[4];
    const f4 z4 = {0.f, 0.f, 0.f, 0.f};
#pragma unroll
    for (int dt = 0; dt < 4; ++dt) o_acc[dt] = z4;

    for (int jt = 0; jt < nt; ++jt) {
        const int buf = jt & 1;
        if (jt + 1 < nt) STAGE(jt + 1, buf ^ 1);   // async prefetch, drains at end barrier
        const _Float16* Ks = KVs[buf][0];
        const _Float16* Vs = KVs[buf][1];

        // S = Q K^T   (swizzled chunk: slot = k-chunk ^ (row&7))
        f4 s_acc[4];
#pragma unroll
        for (int j4 = 0; j4 < 4; ++j4) s_acc[j4] = z4;
#pragma unroll
        for (int j4 = 0; j4 < 4; ++j4) {
            int row = j4 * 16 + t16, rx = row & 7;
            h8 kf0 = *(const h8*)(Ks + (row * 8 + (quad ^ rx)) * 8);
            h8 kf1 = *(const h8*)(Ks + (row * 8 + ((quad + 4) ^ rx)) * 8);
            s_acc[j4] = __builtin_amdgcn_mfma_f32_16x16x32_f16(qf0, kf0, s_acc[j4], 0, 0, 0);
            s_acc[j4] = __builtin_amdgcn_mfma_f32_16x16x32_f16(qf1, kf1, s_acc[j4], 0, 0, 0);
        }

        // causal mask only on the diagonal tile (uniform branch)
        if (jt == nt - 1) {
#pragma unroll
            for (int j4 = 0; j4 < 4; ++j4) {
                int jg = jt * 64 + j4 * 16 + t16;
#pragma unroll
                for (int reg = 0; reg < 4; ++reg) {
                    int ig = q0 + wave * 16 + quad * 4 + reg;
                    if (jg > ig) s_acc[j4][reg] = -1e30f;
                }
            }
        }

        // online softmax in exp2 domain (scale folded into Wq)
        float mrow[4];
#pragma unroll
        for (int reg = 0; reg < 4; ++reg)
            mrow[reg] = fmaxf(fmaxf(s_acc[0][reg], s_acc[1][reg]),
                              fmaxf(s_acc[2][reg], s_acc[3][reg]));
#pragma unroll
        for (int off = 1; off < 16; off <<= 1)
#pragma unroll
            for (int reg = 0; reg < 4; ++reg)
                mrow[reg] = fmaxf(mrow[reg], __shfl_xor(mrow[reg], off, 64));

        float alpha[4];
#pragma unroll
        for (int reg = 0; reg < 4; ++reg) {
            float mn = fmaxf(m_r[reg], mrow[reg]);
            alpha[reg] = __builtin_amdgcn_exp2f(m_r[reg] - mn);
            m_r[reg] = mn;
        }
        float rsum[4] = {0.f, 0.f, 0.f, 0.f};
#pragma unroll
        for (int j4 = 0; j4 < 4; ++j4)
#pragma unroll
            for (int reg = 0; reg < 4; ++reg) {
                float p = __builtin_amdgcn_exp2f(s_acc[j4][reg] - m_r[reg]);
                s_acc[j4][reg] = p;
                rsum[reg] += p;
            }
#pragma unroll
        for (int off = 1; off < 16; off <<= 1)
#pragma unroll
            for (int reg = 0; reg < 4; ++reg)
                rsum[reg] += __shfl_xor(rsum[reg], off, 64);
#pragma unroll
        for (int reg = 0; reg < 4; ++reg)
            l_r[reg] = l_r[reg] * alpha[reg] + rsum[reg];

        // P: C-layout -> LDS f32 (stride 68: full-dword stores, <=2-way banks); same-wave rows only
#pragma unroll
        for (int j4 = 0; j4 < 4; ++j4)
#pragma unroll
            for (int reg = 0; reg < 4; ++reg)
                Ps[(wave * 16 + quad * 4 + reg) * 68 + j4 * 16 + t16] = s_acc[j4][reg];

        // rescale O
#pragma unroll
        for (int dt = 0; dt < 4; ++dt)
#pragma unroll
            for (int reg = 0; reg < 4; ++reg)
                o_acc[dt][reg] *= alpha[reg];

        // P fragments (A-layout) from LDS, cvt f32->f16 in regs
        const float* Pr = Ps + (wave * 16 + t16) * 68;
        float4 p0 = *(const float4*)(Pr + quad * 8);
        float4 p1 = *(const float4*)(Pr + quad * 8 + 4);
        float4 p2 = *(const float4*)(Pr + 32 + quad * 8);
        float4 p3 = *(const float4*)(Pr + 32 + quad * 8 + 4);
        h8 pf0 = { (_Float16)p0.x, (_Float16)p0.y, (_Float16)p0.z, (_Float16)p0.w,
                   (_Float16)p1.x, (_Float16)p1.y, (_Float16)p1.z, (_Float16)p1.w };
        h8 pf1 = { (_Float16)p2.x, (_Float16)p2.y, (_Float16)p2.z, (_Float16)p2.w,
                   (_Float16)p3.x, (_Float16)p3.y, (_Float16)p3.z, (_Float16)p3.w };

        // O += P V
#pragma unroll
        for (int dt = 0; dt < 4; ++dt) {
            int row = dt * 16 + t16, rx = row & 7;
            h8 vf0 = *(const h8*)(Vs + (row * 8 + (quad ^ rx)) * 8);
            h8 vf1 = *(const h8*)(Vs + (row * 8 + ((quad + 4) ^ rx)) * 8);
            o_acc[dt] = __builtin_amdgcn_mfma_f32_16x16x32_f16(pf0, vf0, o_acc[dt], 0, 0, 0);
            o_acc[dt] = __builtin_amdgcn_mfma_f32_16x16x32_f16(pf1, vf1, o_acc[dt], 0, 0, 0);
        }
        __syncthreads();
    }

    // epilogue: O merged-head f16 [B,S,E]
#pragma unroll
    for (int reg = 0; reg < 4; ++reg) {
        float inv = __builtin_amdgcn_rcpf(l_r[reg]);
        int s = q0 + wave * 16 + quad * 4 + reg;
#pragma unroll
        for (int dt = 0; dt < 4; ++dt)
            Ob[((size_t)(b * SEQ + s)) * EMBED + h * DHEAD + dt * 16 + t16] =
                (_Float16)(o_acc[dt][reg] * inv);
    }
}

// ---------------- output projection: out = Ob(f16) * Wo^T, fp32 out ----------------
__global__ __launch_bounds__(256) void proj_out(
    const _Float16* __restrict__ A, const _Float16* __restrict__ Wo, float* __restrict__ out)
{
    __shared__ _Float16 As[4096], Bs[4096];
    const int tid = threadIdx.x;
    const int m0 = blockIdx.x * 128, n0 = blockIdx.y * 128;
    f4 acc[4][4];
    const f4 z4 = {0.f, 0.f, 0.f, 0.f};
#pragma unroll
    for (int i = 0; i < 4; ++i)
#pragma unroll
        for (int j = 0; j < 4; ++j) acc[i][j] = z4;

    gemm_core(A, Wo, m0, n0, tid, As, Bs, acc);

    const int lane = tid & 63, wave = tid >> 6;
    const int t16 = lane & 15, quad = lane >> 4;
    const int wm = (wave >> 1) * 64, wn = (wave & 1) * 64;
#pragma unroll
    for (int i = 0; i < 4; ++i)
#pragma unroll
        for (int j = 0; j < 4; ++j)
#pragma unroll
            for (int reg = 0; reg < 4; ++reg) {
                int gm = m0 + wm + i * 16 + quad * 4 + reg;
                int gn = n0 + wn + j * 16 + t16;
                out[(size_t)gm * EMBED + gn] = acc[i][j][reg];
            }
}

extern "C" void kernel_launch(void* const* d_in, const int* in_sizes, int n_in,
                              void* d_out, int out_size, void* d_ws, size_t ws_size,
                              hipStream_t stream) {
    const float* key   = (const float*)d_in[0];
    const float* query = (const float*)d_in[1];
    const float* value = (const float*)d_in[2];
    // d_in[3] = mask: causal tril, hardcoded
    const float* Wq = (const float*)d_in[4];
    const float* Wk = (const float*)d_in[5];
    const float* Wv = (const float*)d_in[6];
    const float* Wo = (const float*)d_in[7];

    char* ws = (char*)d_ws;
    _Float16* v16  = (_Float16*)(ws);                // 16 MiB (reused as Ob after proj_qkv)
    _Float16* Wq16 = (_Float16*)(ws + (16u << 20));  // 2 MiB
    _Float16* Wk16 = (_Float16*)(ws + (18u << 20));
    _Float16* Wv16 = (_Float16*)(ws + (20u << 20));
    _Float16* Wo16 = (_Float16*)(ws + (22u << 20));
    _Float16* Qh   = (_Float16*)(ws + (24u << 20));  // 16 MiB [B,H,S,d]
    _Float16* Kh   = (_Float16*)(ws + (40u << 20));  // 16 MiB [B,H,S,d]
    _Float16* Vt   = (_Float16*)(ws + (56u << 20));  // 16 MiB [B,H,d,S]  (total ws: 72 MiB)
    _Float16* Ob   = v16;                            // alias: v16 dead after proj_qkv
    // d_out (32 MiB fp32) doubles as scratch for the f16 activation copies until proj_out
    _Float16* q16 = (_Float16*)d_out;
    _Float16* k16 = (_Float16*)d_out + 8388608;

    dim3 blk(256);
    cvt_f16<<<dim3(28672), blk, 0, stream>>>(query, key, value, Wq, Wk, Wv, Wo,
                                             q16, k16, v16, Wq16, Wk16, Wv16, Wo16);
    proj_qkv<<<dim3(64, 8, 3), blk, 0, stream>>>(q16, k16, v16, Wq16, Wk16, Wv16, Qh, Kh, Vt);
    attn2<<<dim3(64, 32), blk, 0, stream>>>(Qh, Kh, Vt, Ob);
    proj_out<<<dim3(64, 8), blk, 0, stream>>>(Ob, Wo16, (float*)d_out);
}

// Round 3
// 338.797 us; speedup vs baseline: 1.4175x; 1.1497x over previous
//
#include <hip/hip_runtime.h>

#define SEQ 2048
#define EMBED 1024
#define DHEAD 64

typedef _Float16 h8 __attribute__((ext_vector_type(8)));
typedef _Float16 h4 __attribute__((ext_vector_type(4)));
typedef float f4 __attribute__((ext_vector_type(4)));
typedef unsigned int u32;

// async global->LDS 16B copy. LDS dest is wave-uniform base + lane*16.
__device__ __forceinline__ void gload_lds16(const void* g, void* l) {
    __builtin_amdgcn_global_load_lds(
        (const __attribute__((address_space(1))) u32*)g,
        (__attribute__((address_space(3))) u32*)l, 16, 0, 0);
}

// ---------------- fp32 -> f16 conversion pass (Wq pre-scaled by 0.125*log2(e)) ----------------
__global__ __launch_bounds__(256) void cvt_f16(
    const float* __restrict__ q, const float* __restrict__ k, const float* __restrict__ v,
    const float* __restrict__ wq, const float* __restrict__ wk, const float* __restrict__ wv,
    const float* __restrict__ wo,
    _Float16* __restrict__ q16, _Float16* __restrict__ k16, _Float16* __restrict__ v16,
    _Float16* __restrict__ wq16, _Float16* __restrict__ wk16, _Float16* __restrict__ wv16,
    _Float16* __restrict__ wo16)
{
    int bid = blockIdx.x;
    const float* src;
    _Float16* dst;
    float scale = 1.0f;
    size_t base;
    if (bid < 24576) {
        int seg = bid >> 13;
        base = (size_t)(bid & 8191) * 1024 + threadIdx.x * 4;
        src = seg == 0 ? q : seg == 1 ? k : v;
        dst = seg == 0 ? q16 : seg == 1 ? k16 : v16;
    } else {
        int wb = bid - 24576;
        int seg = wb >> 10;
        base = (size_t)(wb & 1023) * 1024 + threadIdx.x * 4;
        src = seg == 0 ? wq : seg == 1 ? wk : seg == 2 ? wv : wo;
        dst = seg == 0 ? wq16 : seg == 1 ? wk16 : seg == 2 ? wv16 : wo16;
        if (seg == 0) scale = 0.18033688011112042f;  // 0.125 * log2(e)
    }
    float4 x = *(const float4*)(src + base);
    h4 y = { (_Float16)(x.x * scale), (_Float16)(x.y * scale),
             (_Float16)(x.z * scale), (_Float16)(x.w * scale) };
    *(h4*)(dst + base) = y;
}

// ---------------- m97-style f16 GEMM core: C[128x128] = A * W^T, K=1024, BK=32 ----------------
__device__ __forceinline__ void gemm_core(const _Float16* __restrict__ A, const _Float16* __restrict__ W,
                                          int m0, int n0, int tid,
                                          _Float16* As, _Float16* Bs, f4 acc[4][4])
{
    const int lane = tid & 63, wave = tid >> 6;
    const int t16 = lane & 15, quad = lane >> 4;
    const int wm = (wave >> 1) * 64, wn = (wave & 1) * 64;
    const int wb = wave * 64;
    const int u0 = tid, u1 = tid + 256;
    const int r0 = u0 >> 2, c0 = u0 & 3;
    const int r1 = u1 >> 2, c1 = u1 & 3;
    const _Float16* ga0 = A + (size_t)(m0 + r0) * 1024 + c0 * 8;
    const _Float16* ga1 = A + (size_t)(m0 + r1) * 1024 + c1 * 8;
    const _Float16* gb0 = W + (size_t)(n0 + r0) * 1024 + c0 * 8;
    const _Float16* gb1 = W + (size_t)(n0 + r1) * 1024 + c1 * 8;
    _Float16* la0 = As + wb * 8;
    _Float16* la1 = As + (256 + wb) * 8;
    _Float16* lb0 = Bs + wb * 8;
    _Float16* lb1 = Bs + (256 + wb) * 8;

    for (int k0 = 0; k0 < 1024; k0 += 32) {
        __syncthreads();
        gload_lds16(ga0 + k0, la0);
        gload_lds16(ga1 + k0, la1);
        gload_lds16(gb0 + k0, lb0);
        gload_lds16(gb1 + k0, lb1);
        __syncthreads();
        h8 af[4], bf[4];
#pragma unroll
        for (int i = 0; i < 4; ++i)
            af[i] = *(const h8*)(As + (wm + i * 16 + t16) * 32 + quad * 8);
#pragma unroll
        for (int j = 0; j < 4; ++j)
            bf[j] = *(const h8*)(Bs + (wn + j * 16 + t16) * 32 + quad * 8);
#pragma unroll
        for (int i = 0; i < 4; ++i)
#pragma unroll
            for (int j = 0; j < 4; ++j)
                acc[i][j] = __builtin_amdgcn_mfma_f32_16x16x32_f16(af[i], bf[j], acc[i][j], 0, 0, 0);
    }
}

// ---------------- fused QKV projection ----------------
__global__ __launch_bounds__(256) void proj_qkv(
    const _Float16* __restrict__ q16, const _Float16* __restrict__ k16, const _Float16* __restrict__ v16,
    const _Float16* __restrict__ Wq, const _Float16* __restrict__ Wk, const _Float16* __restrict__ Wv,
    _Float16* __restrict__ Qh, _Float16* __restrict__ Kh, _Float16* __restrict__ Vt)
{
    __shared__ _Float16 As[4096], Bs[4096];
    const int tid = threadIdx.x;
    const int z = blockIdx.z;
    const _Float16 *A, *W;
    int m0, n0;
    if (z == 2) { A = Wv; W = v16; m0 = blockIdx.y * 128; n0 = blockIdx.x * 128; }
    else if (z == 0) { A = q16; W = Wq; m0 = blockIdx.x * 128; n0 = blockIdx.y * 128; }
    else { A = k16; W = Wk; m0 = blockIdx.x * 128; n0 = blockIdx.y * 128; }

    f4 acc[4][4];
    const f4 z4 = {0.f, 0.f, 0.f, 0.f};
#pragma unroll
    for (int i = 0; i < 4; ++i)
#pragma unroll
        for (int j = 0; j < 4; ++j) acc[i][j] = z4;

    gemm_core(A, W, m0, n0, tid, As, Bs, acc);

    const int lane = tid & 63, wave = tid >> 6;
    const int t16 = lane & 15, quad = lane >> 4;
    const int wm = (wave >> 1) * 64, wn = (wave & 1) * 64;
#pragma unroll
    for (int i = 0; i < 4; ++i)
#pragma unroll
        for (int j = 0; j < 4; ++j)
#pragma unroll
            for (int reg = 0; reg < 4; ++reg) {
                int gm = m0 + wm + i * 16 + quad * 4 + reg;
                int gn = n0 + wn + j * 16 + t16;
                float vv = acc[i][j][reg];
                if (z < 2) {
                    int b = gm >> 11, s = gm & 2047, h = gn >> 6, dd = gn & 63;
                    _Float16* dst = (z == 0) ? Qh : Kh;
                    dst[(((size_t)(b * 16 + h) * SEQ) + s) * DHEAD + dd] = (_Float16)vv;
                } else {
                    int h = gm >> 6, dd = gm & 63, b = gn >> 11, s = gn & 2047;
                    Vt[(((size_t)(b * 16 + h) * DHEAD) + dd) * SEQ + s] = (_Float16)vv;
                }
            }
}

// ---------------- causal flash attention v3 ----------------
// block = (b,h) x 128 q-rows; wave w owns q [q0+w*32, +32) as 2 q-blocks of 16.
// S^T = K.Q^T (col=q -> softmax is in-lane + 2 shuffles); PV as O^T = V^T.P^T.
// All K/V LDS tiles stored fragment-major (base + lane*16) -> conflict-free b128 reads.
// P^T exchange is same-wave via LDS (no barrier). 1 barrier per j-tile.
__global__ __launch_bounds__(256) void attn3(
    const _Float16* __restrict__ Qh, const _Float16* __restrict__ Kh,
    const _Float16* __restrict__ Vt, _Float16* __restrict__ Ob)
{
    __shared__ _Float16 Kbuf[2][8][512];   // [buf][j4*2+kc][lane*8]
    __shared__ _Float16 Vbuf[2][8][512];   // [buf][dt*2+kc][lane*8]
    __shared__ _Float16 Pex[4][2][2][512]; // [wave][qblock][kc][lane*8]

    const int tid = threadIdx.x;
    const int lane = tid & 63, wave = tid >> 6;
    const int t16 = lane & 15, quad = lane >> 4;
    const int bh = blockIdx.x;
    const int b = bh >> 4, h = bh & 15;
    const int qb = (gridDim.y - 1) - blockIdx.y;   // heavy blocks first
    const int q0 = qb * 128;
    const int nqt = qb * 2 + 2;

    const _Float16* Qp = Qh + (size_t)bh * SEQ * DHEAD;
    const _Float16* Kp = Kh + (size_t)bh * SEQ * DHEAD;
    const _Float16* Vp = Vt + (size_t)bh * DHEAD * SEQ;

    const int qlo[2] = { q0 + wave * 32, q0 + wave * 32 + 16 };
    const int last0 = (qlo[0] + 15) >> 6;
    const int last1 = (qlo[1] + 15) >> 6;

    // Q fragments (B-operand: lane holds Q[q=t16-row][d=quad*8+j])
    h8 qf[2][2];
#pragma unroll
    for (int qb2 = 0; qb2 < 2; ++qb2)
#pragma unroll
        for (int kc = 0; kc < 2; ++kc)
            qf[qb2][kc] = *(const h8*)(Qp + (size_t)(qlo[qb2] + t16) * 64 + kc * 32 + quad * 8);

    // per-lane staging bases (fragment-major: lane (quad,t16) loads row t16 of its group)
    const _Float16* Kl = Kp + t16 * 64 + quad * 8;
    const _Float16* Vl = Vp + t16 * 2048 + quad * 8;

#define STAGE(jt_, bufi)                                                                  \
    do {                                                                                  \
        if (wave < 2) {                                                                   \
            _Pragma("unroll")                                                             \
            for (int i_ = 0; i_ < 4; ++i_) {                                              \
                int g_ = wave * 4 + i_;                                                   \
                gload_lds16(Kl + (jt_) * 4096 + (g_ >> 1) * 1024 + (g_ & 1) * 32,         \
                            &Kbuf[bufi][g_][0]);                                          \
            }                                                                             \
        } else {                                                                          \
            _Pragma("unroll")                                                             \
            for (int i_ = 0; i_ < 4; ++i_) {                                              \
                int g_ = (wave - 2) * 4 + i_;                                             \
                gload_lds16(Vl + (g_ >> 1) * 32768 + (jt_) * 64 + (g_ & 1) * 32,          \
                            &Vbuf[bufi][g_][0]);                                          \
            }                                                                             \
        }                                                                                 \
    } while (0)

    STAGE(0, 0);
    __syncthreads();

    float mv[2] = {-1e30f, -1e30f};
    float lv[2] = {0.f, 0.f};
    f4 o_acc[2][4];
    const f4 z4 = {0.f, 0.f, 0.f, 0.f};
#pragma unroll
    for (int qb2 = 0; qb2 < 2; ++qb2)
#pragma unroll
        for (int dt = 0; dt < 4; ++dt) o_acc[qb2][dt] = z4;

    for (int jt = 0; jt < nqt; ++jt) {
        const int buf = jt & 1;
        if (jt + 1 < nqt) STAGE(jt + 1, buf ^ 1);

        if (jt <= last1) {
            // S^T = K.Q^T  (rows k = jt*64 + j4*16 + quad*4 + reg, col q = t16 of q-block)
            f4 s0[4], s1[4];
#pragma unroll
            for (int j4 = 0; j4 < 4; ++j4) {
                h8 kfa = *(const h8*)(&Kbuf[buf][j4 * 2 + 0][lane * 8]);
                h8 kfb = *(const h8*)(&Kbuf[buf][j4 * 2 + 1][lane * 8]);
                s1[j4] = __builtin_amdgcn_mfma_f32_16x16x32_f16(kfa, qf[1][0], z4, 0, 0, 0);
                s1[j4] = __builtin_amdgcn_mfma_f32_16x16x32_f16(kfb, qf[1][1], s1[j4], 0, 0, 0);
                s0[j4] = __builtin_amdgcn_mfma_f32_16x16x32_f16(kfa, qf[0][0], z4, 0, 0, 0);
                s0[j4] = __builtin_amdgcn_mfma_f32_16x16x32_f16(kfb, qf[0][1], s0[j4], 0, 0, 0);
            }

            // per-q-block online softmax + P^T exchange write
            auto softmax_store = [&](f4* s, int qb2) {
                const int myq = qlo[qb2] + t16;
                if ((jt << 6) + 63 > myq - t16 + 15 || true) { /* placeholder no-op */ }
                if ((jt << 6) + 63 > qlo[qb2]) {   // tile touches diagonal for this q-block
#pragma unroll
                    for (int j4 = 0; j4 < 4; ++j4)
#pragma unroll
                        for (int reg = 0; reg < 4; ++reg) {
                            int kk = (jt << 6) + j4 * 16 + quad * 4 + reg;
                            if (kk > myq) s[j4][reg] = -1e30f;
                        }
                }
                float mr = s[0][0];
#pragma unroll
                for (int j4 = 0; j4 < 4; ++j4)
#pragma unroll
                    for (int reg = 0; reg < 4; ++reg) mr = fmaxf(mr, s[j4][reg]);
                mr = fmaxf(mr, __shfl_xor(mr, 16, 64));
                mr = fmaxf(mr, __shfl_xor(mr, 32, 64));
                float mn = fmaxf(mv[qb2], mr);
                float al = __builtin_amdgcn_exp2f(mv[qb2] - mn);
                mv[qb2] = mn;
                float rs = 0.f;
#pragma unroll
                for (int j4 = 0; j4 < 4; ++j4)
#pragma unroll
                    for (int reg = 0; reg < 4; ++reg) {
                        float p = __builtin_amdgcn_exp2f(s[j4][reg] - mn);
                        s[j4][reg] = p;
                        rs += p;
                    }
                rs += __shfl_xor(rs, 16, 64);
                rs += __shfl_xor(rs, 32, 64);
                lv[qb2] = lv[qb2] * al + rs;
#pragma unroll
                for (int dt = 0; dt < 4; ++dt)
#pragma unroll
                    for (int reg = 0; reg < 4; ++reg) o_acc[qb2][dt][reg] *= al;
                // P^T -> B-frag-major LDS (same wave; target lane Lt, 8B store, 2-way banks)
#pragma unroll
                for (int j4 = 0; j4 < 4; ++j4) {
                    int Lt = (((j4 & 1) * 2 + (quad >> 1)) << 4) + t16;
                    h4 ph = { (_Float16)s[j4][0], (_Float16)s[j4][1],
                              (_Float16)s[j4][2], (_Float16)s[j4][3] };
                    *(h4*)(&Pex[wave][qb2][j4 >> 1][Lt * 8 + (quad & 1) * 4]) = ph;
                }
            };

            if (jt <= last0) {
                softmax_store(s0, 0);
                softmax_store(s1, 1);
                h8 pb0a = *(const h8*)(&Pex[wave][0][0][lane * 8]);
                h8 pb0b = *(const h8*)(&Pex[wave][0][1][lane * 8]);
                h8 pb1a = *(const h8*)(&Pex[wave][1][0][lane * 8]);
                h8 pb1b = *(const h8*)(&Pex[wave][1][1][lane * 8]);
#pragma unroll
                for (int dt = 0; dt < 4; ++dt) {
                    h8 ava = *(const h8*)(&Vbuf[buf][dt * 2 + 0][lane * 8]);
                    h8 avb = *(const h8*)(&Vbuf[buf][dt * 2 + 1][lane * 8]);
                    o_acc[0][dt] = __builtin_amdgcn_mfma_f32_16x16x32_f16(ava, pb0a, o_acc[0][dt], 0, 0, 0);
                    o_acc[0][dt] = __builtin_amdgcn_mfma_f32_16x16x32_f16(avb, pb0b, o_acc[0][dt], 0, 0, 0);
                    o_acc[1][dt] = __builtin_amdgcn_mfma_f32_16x16x32_f16(ava, pb1a, o_acc[1][dt], 0, 0, 0);
                    o_acc[1][dt] = __builtin_amdgcn_mfma_f32_16x16x32_f16(avb, pb1b, o_acc[1][dt], 0, 0, 0);
                }
            } else {
                softmax_store(s1, 1);
                h8 pb1a = *(const h8*)(&Pex[wave][1][0][lane * 8]);
                h8 pb1b = *(const h8*)(&Pex[wave][1][1][lane * 8]);
#pragma unroll
                for (int dt = 0; dt < 4; ++dt) {
                    h8 ava = *(const h8*)(&Vbuf[buf][dt * 2 + 0][lane * 8]);
                    h8 avb = *(const h8*)(&Vbuf[buf][dt * 2 + 1][lane * 8]);
                    o_acc[1][dt] = __builtin_amdgcn_mfma_f32_16x16x32_f16(ava, pb1a, o_acc[1][dt], 0, 0, 0);
                    o_acc[1][dt] = __builtin_amdgcn_mfma_f32_16x16x32_f16(avb, pb1b, o_acc[1][dt], 0, 0, 0);
                }
            }
        }
        __syncthreads();
    }

    // epilogue: O^T -> (same-wave LDS transpose) -> coalesced f16 [B,S,E] store
#pragma unroll
    for (int qb2 = 0; qb2 < 2; ++qb2) {
        float inv = __builtin_amdgcn_rcpf(lv[qb2]);
        _Float16* ep = &Pex[wave][qb2][0][0];   // 1024 halves: [q=16][d=64]
#pragma unroll
        for (int dt = 0; dt < 4; ++dt) {
            h4 ov = { (_Float16)(o_acc[qb2][dt][0] * inv), (_Float16)(o_acc[qb2][dt][1] * inv),
                      (_Float16)(o_acc[qb2][dt][2] * inv), (_Float16)(o_acc[qb2][dt][3] * inv) };
            *(h4*)(ep + t16 * 64 + dt * 16 + quad * 4) = ov;
        }
        h8 r0 = *(const h8*)(ep + t16 * 64 + quad * 8);
        h8 r1 = *(const h8*)(ep + t16 * 64 + 32 + quad * 8);
        int s = qlo[qb2] + t16;
        _Float16* og = Ob + ((size_t)(b * SEQ + s)) * EMBED + h * DHEAD;
        *(h8*)(og + quad * 8) = r0;
        *(h8*)(og + 32 + quad * 8) = r1;
    }
#undef STAGE
}

// ---------------- output projection: out = Ob(f16) * Wo^T, fp32 out ----------------
__global__ __launch_bounds__(256) void proj_out(
    const _Float16* __restrict__ A, const _Float16* __restrict__ Wo, float* __restrict__ out)
{
    __shared__ _Float16 As[4096], Bs[4096];
    const int tid = threadIdx.x;
    const int m0 = blockIdx.x * 128, n0 = blockIdx.y * 128;
    f4 acc[4][4];
    const f4 z4 = {0.f, 0.f, 0.f, 0.f};
#pragma unroll
    for (int i = 0; i < 4; ++i)
#pragma unroll
        for (int j = 0; j < 4; ++j) acc[i][j] = z4;

    gemm_core(A, Wo, m0, n0, tid, As, Bs, acc);

    const int lane = tid & 63, wave = tid >> 6;
    const int t16 = lane & 15, quad = lane >> 4;
    const int wm = (wave >> 1) * 64, wn = (wave & 1) * 64;
#pragma unroll
    for (int i = 0; i < 4; ++i)
#pragma unroll
        for (int j = 0; j < 4; ++j)
#pragma unroll
            for (int reg = 0; reg < 4; ++reg) {
                int gm = m0 + wm + i * 16 + quad * 4 + reg;
                int gn = n0 + wn + j * 16 + t16;
                out[(size_t)gm * EMBED + gn] = acc[i][j][reg];
            }
}

extern "C" void kernel_launch(void* const* d_in, const int* in_sizes, int n_in,
                              void* d_out, int out_size, void* d_ws, size_t ws_size,
                              hipStream_t stream) {
    const float* key   = (const float*)d_in[0];
    const float* query = (const float*)d_in[1];
    const float* value = (const float*)d_in[2];
    // d_in[3] = mask: causal tril, hardcoded
    const float* Wq = (const float*)d_in[4];
    const float* Wk = (const float*)d_in[5];
    const float* Wv = (const float*)d_in[6];
    const float* Wo = (const float*)d_in[7];

    char* ws = (char*)d_ws;
    _Float16* v16  = (_Float16*)(ws);                // 16 MiB (reused as Ob after proj_qkv)
    _Float16* Wq16 = (_Float16*)(ws + (16u << 20));  // 2 MiB each
    _Float16* Wk16 = (_Float16*)(ws + (18u << 20));
    _Float16* Wv16 = (_Float16*)(ws + (20u << 20));
    _Float16* Wo16 = (_Float16*)(ws + (22u << 20));
    _Float16* Qh   = (_Float16*)(ws + (24u << 20));  // 16 MiB [B,H,S,d]
    _Float16* Kh   = (_Float16*)(ws + (40u << 20));  // 16 MiB [B,H,S,d]
    _Float16* Vt   = (_Float16*)(ws + (56u << 20));  // 16 MiB [B,H,d,S]
    _Float16* Ob   = v16;                            // alias: v16 dead after proj_qkv
    _Float16* q16 = (_Float16*)d_out;                // d_out doubles as scratch until proj_out
    _Float16* k16 = (_Float16*)d_out + 8388608;

    dim3 blk(256);
    cvt_f16<<<dim3(28672), blk, 0, stream>>>(query, key, value, Wq, Wk, Wv, Wo,
                                             q16, k16, v16, Wq16, Wk16, Wv16, Wo16);
    proj_qkv<<<dim3(64, 8, 3), blk, 0, stream>>>(q16, k16, v16, Wq16, Wk16, Wv16, Qh, Kh, Vt);
    attn3<<<dim3(64, 16), blk, 0, stream>>>(Qh, Kh, Vt, Ob);
    proj_out<<<dim3(64, 8), blk, 0, stream>>>(Ob, Wo16, (float*)d_out);
}